// Round 3
// baseline (70.577 us; speedup 1.0000x reference)
//
#include <hip/hip_runtime.h>

#define NB 32
#define RR 128
#define FF 128
#define FH 64   // f processed in two halves so the b-tile fits the 64 KB workgroup LDS limit
#define SBJ 68  // dwords per j-row in the LDS half-tile (64 + 4 pad; 272 B keeps 16 B align,
                // and 68 % 32 == 4 spreads b128 reads evenly over banks)

// ds(i,j) = ||x1_i - x2_j - m||^2 = ca_i + cb_j - 2*dot(x1_i, x2_j)
//   ca_i = sum_f u(u-2m) + 128 m^2   (u = raw x1)
//   cb_j = sum_f v(v+2m)             (v = raw x2)
// so the hot loop is a pure dot product: raw x1 rows come in through SGPRs
// (wave-uniform scalar loads -> zero LDS/VALU-bandwidth A operand), raw x2
// through one LDS b-tile staged per block. kernel k = exp(cneg*ds) is in
// (0,1], so softmax over j is safe WITHOUT max subtraction: out = e^k / sum.
//
// Block = (n, 16 i-rows): 256 thr = 4 waves, wave = 4 rows x 128 j
// (lane owns j = lane and lane+64). Grid 256 = 1 block/CU.
__global__ __launch_bounds__(256) void gauss_v3(const float* __restrict__ x1,
                                                const float* __restrict__ x2,
                                                const float* __restrict__ sigma,
                                                const float* __restrict__ mean,
                                                float* __restrict__ out) {
  __shared__ __align__(16) float sh_b[RR * SBJ];  // 34.8 KB half-tile [j][f]
  __shared__ float sh_red[256];
  __shared__ float sh_ca[16];
  __shared__ float sh_cb[RR];

  const int tid = threadIdx.x;
  const int bid = blockIdx.x;
  const int n = bid >> 3;
  const int i0 = (bid & 7) << 4;  // 16 rows per block

  const float mval = mean[0];
  const float sg = sigma[0];
  const float cneg = -1.0f / (2.0f * sg * sg);
  const float m2 = 2.0f * mval;

  // --- ca_i for the block's 16 rows: thread t covers row t>>4, f-part (t&15)*8
  {
    const int r = tid >> 4, p = tid & 15;
    const float4* src = (const float4*)(x1 + ((size_t)(n * RR + i0 + r)) * FF + p * 8);
    const float4 v0 = src[0], v1 = src[1];
    sh_red[tid] = v0.x * (v0.x - m2) + v0.y * (v0.y - m2) + v0.z * (v0.z - m2) +
                  v0.w * (v0.w - m2) + v1.x * (v1.x - m2) + v1.y * (v1.y - m2) +
                  v1.z * (v1.z - m2) + v1.w * (v1.w - m2);
  }
  __syncthreads();
  if (tid < 16) {
    float s = 0.f;
#pragma unroll
    for (int p = 0; p < 16; ++p) s += sh_red[tid * 16 + p];
    sh_ca[tid] = s + (float)FF * mval * mval;
  }

  const int lane = tid & 63;
  const int wv = __builtin_amdgcn_readfirstlane(tid >> 6);  // force SGPR row base
  const float* __restrict__ arow0 = x1 + ((size_t)(n * RR + i0 + wv * 4)) * FF;

  const int js = tid >> 1;         // staging: thread pair (t, t^1) covers row j = t>>1
  const int fo = (tid & 1) << 5;   // f-offset 0 / 32 within the 64-f half
  const float* __restrict__ x2n = x2 + (size_t)n * RR * FF;

  float acc[4][2] = {{0.f, 0.f}, {0.f, 0.f}, {0.f, 0.f}, {0.f, 0.f}};
  float cbp = 0.f;

  for (int h = 0; h < 2; ++h) {
    __syncthreads();  // prior half's reads done before restaging sh_b
    {
      const float4* src = (const float4*)(x2n + (size_t)js * FF + h * FH + fo);
      float4* dst = (float4*)(sh_b + js * SBJ + fo);
#pragma unroll
      for (int c = 0; c < 8; ++c) {
        const float4 v = src[c];
        dst[c] = v;  // ds_write_b128, straight copy (no transpose, no conflicts)
        cbp += v.x * (v.x + m2) + v.y * (v.y + m2) + v.z * (v.z + m2) + v.w * (v.w + m2);
      }
    }
    __syncthreads();

    const float4* __restrict__ b0 = (const float4*)(sh_b + lane * SBJ);
    const float4* __restrict__ b1 = (const float4*)(sh_b + (lane + 64) * SBJ);
#pragma unroll
    for (int fq = 0; fq < FH / 4; ++fq) {
      const float4 v0 = b0[fq];  // 2 ds_read_b128 feed 32 fma
      const float4 v1 = b1[fq];
#pragma unroll
      for (int r = 0; r < 4; ++r) {
        // wave-uniform address -> s_load_dwordx4 (A operand via SGPRs)
        const float4 a = *(const float4*)(arow0 + r * FF + h * FH + fq * 4);
        acc[r][0] = fmaf(a.x, v0.x, acc[r][0]);
        acc[r][0] = fmaf(a.y, v0.y, acc[r][0]);
        acc[r][0] = fmaf(a.z, v0.z, acc[r][0]);
        acc[r][0] = fmaf(a.w, v0.w, acc[r][0]);
        acc[r][1] = fmaf(a.x, v1.x, acc[r][1]);
        acc[r][1] = fmaf(a.y, v1.y, acc[r][1]);
        acc[r][1] = fmaf(a.z, v1.z, acc[r][1]);
        acc[r][1] = fmaf(a.w, v1.w, acc[r][1]);
      }
    }
  }

  // finalize cb_j: pair (t, t^1) together covered all 128 f for j = t>>1
  {
    const float other = __shfl_xor(cbp, 1, 64);
    if ((tid & 1) == 0) sh_cb[js] = cbp + other;
  }
  __syncthreads();

  // epilogue: k = exp(cneg*ds) in (0,1]; softmax over j without max-subtract
  const int j1 = lane + 64;
  const float cb0 = sh_cb[lane];
  const float cb1 = sh_cb[j1];
  float* __restrict__ orow = out + ((size_t)(n * RR + i0 + wv * 4)) * RR;
#pragma unroll
  for (int r = 0; r < 4; ++r) {
    const float ca = sh_ca[wv * 4 + r];
    const float k0 = __expf(cneg * (ca + cb0 - 2.f * acc[r][0]));
    const float k1 = __expf(cneg * (ca + cb1 - 2.f * acc[r][1]));
    const float e0 = __expf(k0);
    const float e1 = __expf(k1);
    float s = e0 + e1;  // row's 128 values live in 64 lanes x 2 regs
#pragma unroll
    for (int off = 32; off >= 1; off >>= 1) s += __shfl_xor(s, off, 64);
    const float inv = 1.0f / s;
    orow[r * RR + lane] = e0 * inv;
    orow[r * RR + j1] = e1 * inv;
  }
}

extern "C" void kernel_launch(void* const* d_in, const int* in_sizes, int n_in,
                              void* d_out, int out_size, void* d_ws, size_t ws_size,
                              hipStream_t stream) {
  const float* x1 = (const float*)d_in[0];
  const float* x2 = (const float*)d_in[1];
  const float* sigma = (const float*)d_in[2];
  const float* mean = (const float*)d_in[3];
  float* out = (float*)d_out;
  (void)d_ws; (void)ws_size;

  gauss_v3<<<dim3(NB * 8), dim3(256), 0, stream>>>(x1, x2, sigma, mean, out);
}

// Round 4
// 70.384 us; speedup vs baseline: 1.0027x; 1.0027x over previous
//
#include <hip/hip_runtime.h>

#define NB 32
#define RR 128
#define FF 128
#define FH 64   // f half: b-tile staged twice so it fits the 64 KB workgroup LDS limit
#define SBJ 68  // dwords per j-row: stride 272 B = 4 banks mod 32 -> b128 reads hit the
                // minimum 8 bank-passes (full rate); 16 B aligned

// ds(i,j) = ||x1_i - x2_j - m||^2 = ca_i + cb_j - 2*dot(x1_i, x2_j)
//   ca_i = sum_f u(u-2m) + 128 m^2   (u = raw x1)
//   cb_j = sum_f v(v+2m)             (v = raw x2)
// Hot loop is a pure dot: B from LDS [j][f] (lane-indexed ds_read_b128),
// A from LDS via wave-uniform-address ds_read_b128 (broadcast, conflict-free)
// -- v3's hot-loop GLOBAL A-reads were the stall (200+ cyc latency, 1
// wave/SIMD, nothing to hide it; R3 showed no gain over R2).
// k = exp(cneg*ds) is in (0,1], so softmax over j needs no max-subtract.
//
// Block = (n, 16 i-rows), 256 thr = 4 waves; wave owns 4 rows x 128 j
// (lane holds j = lane and lane+64). Grid 256 = 1 block/CU.
__global__ __launch_bounds__(256) void gauss_v4(const float* __restrict__ x1,
                                                const float* __restrict__ x2,
                                                const float* __restrict__ sigma,
                                                const float* __restrict__ mean,
                                                float* __restrict__ out) {
  __shared__ __align__(16) float sh_b[RR * SBJ];  // 34.8 KB b half-tile [j][f]
  __shared__ __align__(16) float sh_a[16 * FF];   // 8 KB raw x1 rows
  __shared__ float sh_red[256];
  __shared__ float sh_ca[16];
  __shared__ float sh_cb[RR];

  const int tid = threadIdx.x;
  const int bid = blockIdx.x;
  const int n = bid >> 3;
  const int i0 = (bid & 7) << 4;  // 16 rows per block

  const float mval = mean[0];
  const float sg = sigma[0];
  const float cneg = -1.0f / (2.0f * sg * sg);
  const float m2 = 2.0f * mval;

  // Stage 16 raw x1 rows -> sh_a AND accumulate ca partials in one pass.
  // Thread t: row t>>4, f-part (t&15)*8 (two float4).
  {
    const int r = tid >> 4, p = (tid & 15) << 3;
    const float4* src = (const float4*)(x1 + ((size_t)(n * RR + i0 + r)) * FF + p);
    const float4 v0 = src[0], v1 = src[1];
    float4* dst = (float4*)(sh_a + r * FF + p);
    dst[0] = v0;
    dst[1] = v1;
    sh_red[tid] = v0.x * (v0.x - m2) + v0.y * (v0.y - m2) + v0.z * (v0.z - m2) +
                  v0.w * (v0.w - m2) + v1.x * (v1.x - m2) + v1.y * (v1.y - m2) +
                  v1.z * (v1.z - m2) + v1.w * (v1.w - m2);
  }
  __syncthreads();
  if (tid < 16) {
    float s = 0.f;
#pragma unroll
    for (int p = 0; p < 16; ++p) s += sh_red[tid * 16 + p];
    sh_ca[tid] = s + (float)FF * mval * mval;  // read in epilogue (sync'd by h-loop)
  }

  const int lane = tid & 63;
  const int wv = __builtin_amdgcn_readfirstlane(tid >> 6);
  const int r0 = wv << 2;  // this wave's first row

  const int js = tid >> 1;        // staging: pair (t, t^1) covers row j = t>>1
  const int fo = (tid & 1) << 5;  // f-offset 0 / 32 within the 64-f half
  const float* __restrict__ x2n = x2 + (size_t)n * RR * FF;

  float acc[4][2] = {{0.f, 0.f}, {0.f, 0.f}, {0.f, 0.f}, {0.f, 0.f}};
  float cbp = 0.f;

  for (int h = 0; h < 2; ++h) {
    __syncthreads();  // prior half's sh_b reads done before restaging
    {
      const float4* src = (const float4*)(x2n + (size_t)js * FF + h * FH + fo);
      float4* dst = (float4*)(sh_b + js * SBJ + fo);
#pragma unroll
      for (int c = 0; c < 8; ++c) {
        const float4 v = src[c];
        dst[c] = v;  // ds_write_b128, no transpose, bank-clean
        cbp += v.x * (v.x + m2) + v.y * (v.y + m2) + v.z * (v.z + m2) + v.w * (v.w + m2);
      }
    }
    __syncthreads();

    const float4* __restrict__ b0 = (const float4*)(sh_b + lane * SBJ);
    const float4* __restrict__ b1 = (const float4*)(sh_b + (lane + 64) * SBJ);
#pragma unroll
    for (int fq = 0; fq < FH / 4; ++fq) {
      const float4 v0 = b0[fq];  // lane-indexed ds_read_b128, full rate
      const float4 v1 = b1[fq];
#pragma unroll
      for (int r = 0; r < 4; ++r) {
        // wave-uniform LDS address -> broadcast ds_read_b128 (conflict-free)
        const float4 a = *(const float4*)(sh_a + (r0 + r) * FF + h * FH + fq * 4);
        acc[r][0] = fmaf(a.x, v0.x, acc[r][0]);
        acc[r][0] = fmaf(a.y, v0.y, acc[r][0]);
        acc[r][0] = fmaf(a.z, v0.z, acc[r][0]);
        acc[r][0] = fmaf(a.w, v0.w, acc[r][0]);
        acc[r][1] = fmaf(a.x, v1.x, acc[r][1]);
        acc[r][1] = fmaf(a.y, v1.y, acc[r][1]);
        acc[r][1] = fmaf(a.z, v1.z, acc[r][1]);
        acc[r][1] = fmaf(a.w, v1.w, acc[r][1]);
      }
    }
  }

  // finalize cb_j: pair (t, t^1) covered all 128 f for j = t>>1
  {
    const float other = __shfl_xor(cbp, 1, 64);
    if ((tid & 1) == 0) sh_cb[js] = cbp + other;
  }
  __syncthreads();

  // epilogue: k = exp(cneg*ds) in (0,1]; softmax over j without max-subtract
  const int j1 = lane + 64;
  const float cb0 = sh_cb[lane];
  const float cb1 = sh_cb[j1];
  float* __restrict__ orow = out + ((size_t)(n * RR + i0 + r0)) * RR;
#pragma unroll
  for (int r = 0; r < 4; ++r) {
    const float ca = sh_ca[r0 + r];
    const float k0 = __expf(cneg * (ca + cb0 - 2.f * acc[r][0]));
    const float k1 = __expf(cneg * (ca + cb1 - 2.f * acc[r][1]));
    const float e0 = __expf(k0);
    const float e1 = __expf(k1);
    float s = e0 + e1;  // row's 128 values: 64 lanes x 2 regs
#pragma unroll
    for (int off = 32; off >= 1; off >>= 1) s += __shfl_xor(s, off, 64);
    const float inv = 1.0f / s;
    orow[r * RR + lane] = e0 * inv;
    orow[r * RR + j1] = e1 * inv;
  }
}

extern "C" void kernel_launch(void* const* d_in, const int* in_sizes, int n_in,
                              void* d_out, int out_size, void* d_ws, size_t ws_size,
                              hipStream_t stream) {
  const float* x1 = (const float*)d_in[0];
  const float* x2 = (const float*)d_in[1];
  const float* sigma = (const float*)d_in[2];
  const float* mean = (const float*)d_in[3];
  float* out = (float*)d_out;
  (void)d_ws; (void)ws_size;

  gauss_v4<<<dim3(NB * 8), dim3(256), 0, stream>>>(x1, x2, sigma, mean, out);
}